// Round 1
// baseline (70.551 us; speedup 1.0000x reference)
//
#include <hip/hip_runtime.h>
#include <math.h>

// Quantization: out = min + (clip(floor((x-min)/step),0,255)+0.5)*step
// step = (max-min)/256, min/max over the whole tensor.

#define BLOCK 256
#define GRID 2048

__global__ __launch_bounds__(BLOCK) void minmax_kernel(
    const float* __restrict__ x, long long n, float* __restrict__ partial, int nblocks) {
    long long tid = (long long)blockIdx.x * blockDim.x + threadIdx.x;
    long long stride = (long long)gridDim.x * blockDim.x;
    float vmin = INFINITY, vmax = -INFINITY;
    long long n4 = n >> 2;
    const float4* __restrict__ x4 = (const float4*)x;
    for (long long i = tid; i < n4; i += stride) {
        float4 v = x4[i];
        vmin = fminf(vmin, fminf(fminf(v.x, v.y), fminf(v.z, v.w)));
        vmax = fmaxf(vmax, fmaxf(fmaxf(v.x, v.y), fmaxf(v.z, v.w)));
    }
    // tail (n not multiple of 4)
    for (long long i = (n4 << 2) + tid; i < n; i += stride) {
        float v = x[i];
        vmin = fminf(vmin, v);
        vmax = fmaxf(vmax, v);
    }
    // 64-lane wave reduce
    #pragma unroll
    for (int off = 32; off > 0; off >>= 1) {
        vmin = fminf(vmin, __shfl_down(vmin, off, 64));
        vmax = fmaxf(vmax, __shfl_down(vmax, off, 64));
    }
    __shared__ float smin[BLOCK / 64], smax[BLOCK / 64];
    int lane = threadIdx.x & 63;
    int wave = threadIdx.x >> 6;
    if (lane == 0) { smin[wave] = vmin; smax[wave] = vmax; }
    __syncthreads();
    if (threadIdx.x == 0) {
        float bmin = smin[0], bmax = smax[0];
        #pragma unroll
        for (int w = 1; w < BLOCK / 64; ++w) {
            bmin = fminf(bmin, smin[w]);
            bmax = fmaxf(bmax, smax[w]);
        }
        partial[blockIdx.x] = bmin;
        partial[nblocks + blockIdx.x] = bmax;
    }
}

__global__ __launch_bounds__(BLOCK) void final_reduce_kernel(
    const float* __restrict__ partial, int nblocks, float* __restrict__ result) {
    float vmin = INFINITY, vmax = -INFINITY;
    for (int i = threadIdx.x; i < nblocks; i += blockDim.x) {
        vmin = fminf(vmin, partial[i]);
        vmax = fmaxf(vmax, partial[nblocks + i]);
    }
    #pragma unroll
    for (int off = 32; off > 0; off >>= 1) {
        vmin = fminf(vmin, __shfl_down(vmin, off, 64));
        vmax = fmaxf(vmax, __shfl_down(vmax, off, 64));
    }
    __shared__ float smin[BLOCK / 64], smax[BLOCK / 64];
    int lane = threadIdx.x & 63;
    int wave = threadIdx.x >> 6;
    if (lane == 0) { smin[wave] = vmin; smax[wave] = vmax; }
    __syncthreads();
    if (threadIdx.x == 0) {
        float bmin = smin[0], bmax = smax[0];
        #pragma unroll
        for (int w = 1; w < BLOCK / 64; ++w) {
            bmin = fminf(bmin, smin[w]);
            bmax = fmaxf(bmax, smax[w]);
        }
        result[0] = bmin;
        result[1] = bmax;
    }
}

__global__ __launch_bounds__(BLOCK) void quant_kernel(
    const float* __restrict__ x, float* __restrict__ out, long long n,
    const float* __restrict__ mm) {
    const float xmin = mm[0];
    const float xmax = mm[1];
    const float step = (xmax - xmin) * (1.0f / 256.0f);
    const float inv_step = 1.0f / step;

    long long tid = (long long)blockIdx.x * blockDim.x + threadIdx.x;
    long long stride = (long long)gridDim.x * blockDim.x;
    long long n4 = n >> 2;
    const float4* __restrict__ x4 = (const float4*)x;
    float4* __restrict__ o4 = (float4*)out;

    for (long long i = tid; i < n4; i += stride) {
        float4 v = x4[i];
        float4 r;
        float ix = fminf(fmaxf(floorf((v.x - xmin) * inv_step), 0.0f), 255.0f);
        float iy = fminf(fmaxf(floorf((v.y - xmin) * inv_step), 0.0f), 255.0f);
        float iz = fminf(fmaxf(floorf((v.z - xmin) * inv_step), 0.0f), 255.0f);
        float iw = fminf(fmaxf(floorf((v.w - xmin) * inv_step), 0.0f), 255.0f);
        r.x = xmin + (ix + 0.5f) * step;
        r.y = xmin + (iy + 0.5f) * step;
        r.z = xmin + (iz + 0.5f) * step;
        r.w = xmin + (iw + 0.5f) * step;
        o4[i] = r;
    }
    for (long long i = (n4 << 2) + tid; i < n; i += stride) {
        float v = x[i];
        float idx = fminf(fmaxf(floorf((v - xmin) * inv_step), 0.0f), 255.0f);
        out[i] = xmin + (idx + 0.5f) * step;
    }
}

extern "C" void kernel_launch(void* const* d_in, const int* in_sizes, int n_in,
                              void* d_out, int out_size, void* d_ws, size_t ws_size,
                              hipStream_t stream) {
    const float* x = (const float*)d_in[0];
    float* out = (float*)d_out;
    long long n = (long long)in_sizes[0];

    float* ws = (float*)d_ws;
    // layout: ws[0 .. GRID-1] = per-block mins, ws[GRID .. 2*GRID-1] = per-block maxs,
    //         ws[2*GRID], ws[2*GRID+1] = final min, max
    float* partial = ws;
    float* result = ws + 2 * GRID;

    minmax_kernel<<<GRID, BLOCK, 0, stream>>>(x, n, partial, GRID);
    final_reduce_kernel<<<1, BLOCK, 0, stream>>>(partial, GRID, result);
    quant_kernel<<<GRID, BLOCK, 0, stream>>>(x, out, n, result);
}